// Round 9
// baseline (369.466 us; speedup 1.0000x reference)
//
#include <hip/hip_runtime.h>

// Com2Net wavefront kernel, round 11: 2 waves/SIMD + 32-row split-flush ring.
// R10b post-mortem: store RMW fixed exactly as predicted (WRITE 212->65.5MB),
// 170us. Remaining: per-wave stall 830 cyc/step (chain+trans latency) with
// only 1 wave/SIMD -> SIMD idle 52%. Fix: CHUNKS 8->16 (2048 waves = 8/CU =
// 2/SIMD) so a second wave issues during the first's stalls. LDS wall (64-row
// ring = 32KB caps 5 waves/CU) broken by a 32-row SPLIT-FLUSH ring (16KB):
// row p's cols 0..31 complete at step p-t0+31, cols 32..63 at +63; at step u
// ONE 64-lane store flushes cols 0..31 of row t0+u-32 (lanes<32) + cols
// 32..63 of row t0+u-64 (lanes>=32). Both halves sit in ring slot u&31
// (t0 = 0 mod 32 -> slot(row p) = p&31; latest write to (u&31, j) is exactly
// the flushed row). 512B/store = 4 FULL lines -> keeps R10b's no-RMW property.
// Read-at-top / ds_write-after-evals handles the j=0/j=32 same-step boundary
// (same-wave DS ops execute in order). No pend regs, no epilogue: last flush
// (row wend-1, cols 32..63) lands at u = USTEPS-1 inside the ramp.
// Everything else = R10b (R7 MLP, dist-4 prefetch, WARM=64, state guards).

#define T_STEPS 1024
#define N_AGENTS 128
#define CHUNKS 16
#define CLEN (T_STEPS / CHUNKS)      // 64 timesteps written per chunk
#define WARM 64                      // discarded warm-up steps (chunks >= 1)
#define USTEPS (CLEN + WARM + 64)    // 192 macro-steps (mult of 4)

typedef float v2f __attribute__((ext_vector_type(2)));

__device__ __forceinline__ v2f sp(float x) { return (v2f){x, x}; }

// Whole-wave shift-by-1 via DPP. wave_shr1 (0x138): lane i <- lane i-1,
// lane 0 <- 0 (bound_ctrl). wave_shl1 (0x130): lane i <- lane i+1, lane 63 <- 0.
// bound_ctrl zeros are exactly comm[0]/comm[2N+1], which are never written.
__device__ __forceinline__ float wave_shr1(float x) {
    int r = __builtin_amdgcn_update_dpp(0, __builtin_bit_cast(int, x),
                                        0x138, 0xF, 0xF, true);
    return __builtin_bit_cast(float, r);
}
__device__ __forceinline__ float wave_shl1(float x) {
    int r = __builtin_amdgcn_update_dpp(0, __builtin_bit_cast(int, x),
                                        0x130, 0xF, 0xF, true);
    return __builtin_bit_cast(float, r);
}

struct Weights {
    v2f w1x0[5], w1x1[5];    // layer-1 x weights (cols 0,1), * 2*log2(e)
    v2f w1cA[5], w1cB[5];    // layer-1 comm weights (cols 2,3), * 2*log2(e)
    v2f b1[5];               // * 2*log2(e)
    v2f w20[5], w21[5], w22[5];  // = -2 * W2 row r, packed over hidden pairs
    float b20, b21, b22;         // = b2[r] + sum_k W2[r,k]
};

// One S2Net eval, fused (x fmas lead so the scheduler can hoist them into
// the previous phase's stall gaps; cA/cB are the chain-late operands).
// h = sigma = rcp(1 + exp2(a)) per element; tanh affine folded into w2*/b2*.
__device__ __forceinline__ void mlp_eval(const Weights& w, float xa, float xb,
                                         float cA, float cB,
                                         float& o0, float& o1, float& o2) {
    v2f h[5];
#pragma unroll
    for (int p = 0; p < 5; ++p) {
        v2f a = __builtin_elementwise_fma(w.w1x0[p], sp(xa), w.b1[p]);
        a = __builtin_elementwise_fma(w.w1x1[p], sp(xb), a);
        a = __builtin_elementwise_fma(w.w1cB[p], sp(cB), a);
        a = __builtin_elementwise_fma(w.w1cA[p], sp(cA), a);
        v2f t;
        t.x = __builtin_amdgcn_exp2f(a.x);
        t.y = __builtin_amdgcn_exp2f(a.y);
        t = t + (v2f){1.f, 1.f};
        h[p].x = __builtin_amdgcn_rcpf(t.x);
        h[p].y = __builtin_amdgcn_rcpf(t.y);
    }
    // Output dots packed over hidden dim; horizontal add folds the pair.
    v2f a0 = __builtin_elementwise_fma(w.w20[0], h[0], (v2f){w.b20, 0.f});
    v2f a1 = __builtin_elementwise_fma(w.w21[0], h[0], (v2f){w.b21, 0.f});
    v2f a2 = __builtin_elementwise_fma(w.w22[0], h[0], (v2f){w.b22, 0.f});
#pragma unroll
    for (int p = 1; p < 5; ++p) {
        a0 = __builtin_elementwise_fma(w.w20[p], h[p], a0);
        a1 = __builtin_elementwise_fma(w.w21[p], h[p], a1);
        a2 = __builtin_elementwise_fma(w.w22[p], h[p], a2);
    }
    o0 = a0.x + a0.y;
    o1 = a1.x + a1.y;
    o2 = a2.x + a2.y;
}

__global__ void __launch_bounds__(64, 2)
com2net_wavefront(const float* __restrict__ runs,
                  const float* __restrict__ W1, const float* __restrict__ b1,
                  const float* __restrict__ W2, const float* __restrict__ b2,
                  float* __restrict__ out)
{
    const int blk = blockIdx.x;
    const int r   = blk >> 4;              // run index
    const int c   = blk & (CHUNKS - 1);    // time-chunk index
    const int j   = threadIdx.x;           // lane 0..63, owns agents 2j, 2j+1

    const int wstart = c * CLEN;           // first written timestep
    const int wend   = wstart + CLEN;      // one past last written timestep
    const int t0     = wstart - WARM;      // u=0: t = t0 + u - j; t0 = 0 mod 32
    // Chunk 0 must start EXACTLY at t=0 with comm=0 (the reference init).
    const int slo = (c == 0) ? 0 : -0x40000000;

    // 32-row split-flush ring: slot (row & 31), column j. 16 KiB ->
    // 8 blocks/CU at 128 KiB LDS -> 2 waves per SIMD.
    __shared__ v2f ring[32][N_AGENTS / 2];

    const float S = 2.8853900817779268f;  // 2*log2(e), folded into layer 1
    Weights w;
#pragma unroll
    for (int p = 0; p < 5; ++p) {
        w.b1[p]   = (v2f){b1[2 * p] * S, b1[2 * p + 1] * S};
        w.w1x0[p] = (v2f){W1[(2 * p) * 4 + 0] * S, W1[(2 * p + 1) * 4 + 0] * S};
        w.w1x1[p] = (v2f){W1[(2 * p) * 4 + 1] * S, W1[(2 * p + 1) * 4 + 1] * S};
        w.w1cA[p] = (v2f){W1[(2 * p) * 4 + 2] * S, W1[(2 * p + 1) * 4 + 2] * S};
        w.w1cB[p] = (v2f){W1[(2 * p) * 4 + 3] * S, W1[(2 * p + 1) * 4 + 3] * S};
        w.w20[p] = (v2f){-2.f * W2[0 * 10 + 2 * p], -2.f * W2[0 * 10 + 2 * p + 1]};
        w.w21[p] = (v2f){-2.f * W2[1 * 10 + 2 * p], -2.f * W2[1 * 10 + 2 * p + 1]};
        w.w22[p] = (v2f){-2.f * W2[2 * 10 + 2 * p], -2.f * W2[2 * 10 + 2 * p + 1]};
    }
    float s0 = 0.f, s1 = 0.f, s2 = 0.f;
#pragma unroll
    for (int k = 0; k < 10; ++k) {
        s0 += W2[0 * 10 + k];
        s1 += W2[1 * 10 + k];
        s2 += W2[2 * 10 + k];
    }
    w.b20 = b2[0] + s0; w.b21 = b2[1] + s1; w.b22 = b2[2] + s2;

    const float4* __restrict__ xbase =
        (const float4*)(runs + (size_t)r * T_STEPS * N_AGENTS * 2);
    v2f* __restrict__ obase =
        (v2f*)(out + (size_t)r * T_STEPS * N_AGENTS);

    // Replicated recurrence state; zero-init == warm-up / reference init.
    float c1e = 0.f, c2e = 0.f, c1o = 0.f, c2o = 0.f;

    // Clamped row load (OOB lanes re-read row 0/1023; results discarded by
    // the state guards; loads hit cache).
    auto ldrow = [&](int t) -> float4 {
        int tc = t < 0 ? 0 : t;
        tc = tc > T_STEPS - 1 ? T_STEPS - 1 : tc;
        return xbase[tc * (N_AGENTS / 2) + j];
    };

    auto step = [&](int u, const float4& x) {
        // ---- flush read (top of step, BEFORE this step's ds_write): slot
        // u&31 holds cols 0..31 of row t0+u-32 and cols 32..63 of t0+u-64.
        const v2f fv = ring[u & 31][j];
        const int fr = (j < 32) ? (t0 + u - 32) : (t0 + u - 64);

        const int t = t0 + u - j;
        const bool supd = (t >= slo) & (t < wend);

        // ---- even phase: agent 2j at t ----
        float c2pv = wave_shr1(c2o);
        float o0e, o1e, o2e;
        mlp_eval(w, x.x, x.y, c2pv, c1o, o0e, o1e, o2e);
        c1e = supd ? o1e : c1e;
        c2e = supd ? o2e : c2e;

        // ---- odd phase: agent 2j+1 at t ----
        float c1pv = wave_shl1(c1e);
        float o0o, o1o, o2o;
        mlp_eval(w, x.z, x.w, c2e, c1pv, o0o, o1o, o2o);
        c1o = supd ? o1o : c1o;
        c2o = supd ? o2o : c2o;

        // ---- stage this step's outputs: row t0+u-j -> slot (u-j)&31 ----
        // (same-wave DS ops execute in order -> the top-of-step read of the
        // j=0 / j=32 boundary columns happens before this overwrite)
        ring[(unsigned)(u - j) & 31u][j] = (v2f){o0e, o0o};

        // ---- flush store (bottom): one 64-lane store, 4 full cache lines;
        // the ds_read->store distance spans both evals (~700 cyc) so the
        // lgkmcnt wait is satisfied. Predicate kills warm/ramp/garbage rows.
        if ((unsigned)(fr - wstart) < (unsigned)CLEN)
            __builtin_nontemporal_store(
                fv, &obase[(size_t)fr * (N_AGENTS / 2) + j]);
    };

    // Distance-4 register prefetch pipeline, manual unroll-by-4.
    float4 X0 = ldrow(t0 + 0 - j);
    float4 X1 = ldrow(t0 + 1 - j);
    float4 X2 = ldrow(t0 + 2 - j);
    float4 X3 = ldrow(t0 + 3 - j);

    for (int u = 0; u < USTEPS; u += 4) {   // 192 = 4*48 iters
        step(u + 0, X0); X0 = ldrow(t0 + u + 4 - j);
        step(u + 1, X1); X1 = ldrow(t0 + u + 5 - j);
        step(u + 2, X2); X2 = ldrow(t0 + u + 6 - j);
        step(u + 3, X3); X3 = ldrow(t0 + u + 7 - j);
    }
}

extern "C" void kernel_launch(void* const* d_in, const int* in_sizes, int n_in,
                              void* d_out, int out_size, void* d_ws, size_t ws_size,
                              hipStream_t stream) {
    const float* runs = (const float*)d_in[0];
    const float* W1   = (const float*)d_in[1];
    const float* b1   = (const float*)d_in[2];
    const float* W2   = (const float*)d_in[3];
    const float* b2   = (const float*)d_in[4];
    float* out = (float*)d_out;

    const int R = 128;
    com2net_wavefront<<<R * CHUNKS, 64, 0, stream>>>(runs, W1, b1, W2, b2, out);
}

// Round 10
// 313.222 us; speedup vs baseline: 1.1796x; 1.1796x over previous
//
#include <hip/hip_runtime.h>

// Com2Net wavefront kernel, round 12: R10b structure + paired-rcp + WARM=48.
// R11 closed the TLP question: doubling waves/CU gave only +17% raw step
// throughput while warm+ramp overhead grew 50% -> net 0.78x. CHUNKS=8
// (1 wave/SIMD, whole chip, minimal overhead) is the structural optimum.
// R10b = 1602 cyc/step (769 issue + 833 stall). This round trims both:
//   - paired reciprocal (R5-proven numerics): sigma(a)=B*rcp(AB), sigma(b)=
//     A*rcp(AB): 20->10 rcp/step. Nulled out in R5's issue-bound regime
//     (chain +20cyc); here stall(833) >> chain, so the ~80-160 cyc issue
//     saving should convert.
//   - WARM 64->48: R9 proved gain^64 << 2^-8 (absmax bit-identical);
//     gain^48 still orders below the floor. USTEPS 256->240. absmax canary.
//   - ring slots re-derived for WARM=48: slot == in-chunk row & 63 on both
//     write ((m+WARM+SHIFT)&63 = m&63) and read ((m+128)&63 = m&63); read
//     lands exactly 1 step before slot reuse (row m+64 writes start m+112,
//     read at m+111; same-wave DS ops execute in order).

#define T_STEPS 1024
#define N_AGENTS 128
#define CHUNKS 8
#define CLEN (T_STEPS / CHUNKS)      // 128 timesteps written per chunk
#define WARM 48                      // discarded warm-up steps (chunks >= 1)
#define RAMP 64                      // wavefront skew ramp
#define USTEPS (CLEN + WARM + RAMP)  // 240 macro-steps (mult of 4)
#define SHIFT ((64 - (WARM & 63)) & 63)  // t0 mod 64 = 16
#define RD_OFF (WARM + 63)           // in-chunk row m read from ring at u=m+RD_OFF
#define ST_OFF (RD_OFF + 4)          // ...and global-stored 4 steps later

typedef float v2f __attribute__((ext_vector_type(2)));

__device__ __forceinline__ v2f sp(float x) { return (v2f){x, x}; }

// Whole-wave shift-by-1 via DPP. wave_shr1 (0x138): lane i <- lane i-1,
// lane 0 <- 0 (bound_ctrl). wave_shl1 (0x130): lane i <- lane i+1, lane 63 <- 0.
// bound_ctrl zeros are exactly comm[0]/comm[2N+1], which are never written.
__device__ __forceinline__ float wave_shr1(float x) {
    int r = __builtin_amdgcn_update_dpp(0, __builtin_bit_cast(int, x),
                                        0x138, 0xF, 0xF, true);
    return __builtin_bit_cast(float, r);
}
__device__ __forceinline__ float wave_shl1(float x) {
    int r = __builtin_amdgcn_update_dpp(0, __builtin_bit_cast(int, x),
                                        0x130, 0xF, 0xF, true);
    return __builtin_bit_cast(float, r);
}

struct Weights {
    v2f w1x0[5], w1x1[5];    // layer-1 x weights (cols 0,1), * 2*log2(e)
    v2f w1cA[5], w1cB[5];    // layer-1 comm weights (cols 2,3), * 2*log2(e)
    v2f b1[5];               // * 2*log2(e)
    v2f w20[5], w21[5], w22[5];  // = -2 * W2 row r, packed over hidden pairs
    float b20, b21, b22;         // = b2[r] + sum_k W2[r,k]
};

// One S2Net eval, fused (x fmas lead so the scheduler can hoist them into
// the previous phase's stall gaps; cA/cB are the chain-late operands).
// sigma via PAIRED reciprocal: A=1+2^a, B=1+2^b, rr=rcp(A*B),
// h = {B,A}*rr = {sigma(a), sigma(b)}. Overflow-safe: needs preact>44.
// tanh affine folded into w2*/b2* (sigma-fold).
__device__ __forceinline__ void mlp_eval(const Weights& w, float xa, float xb,
                                         float cA, float cB,
                                         float& o0, float& o1, float& o2) {
    v2f h[5];
#pragma unroll
    for (int p = 0; p < 5; ++p) {
        v2f a = __builtin_elementwise_fma(w.w1x0[p], sp(xa), w.b1[p]);
        a = __builtin_elementwise_fma(w.w1x1[p], sp(xb), a);
        a = __builtin_elementwise_fma(w.w1cB[p], sp(cB), a);
        a = __builtin_elementwise_fma(w.w1cA[p], sp(cA), a);
        v2f t;
        t.x = __builtin_amdgcn_exp2f(a.x);
        t.y = __builtin_amdgcn_exp2f(a.y);
        t = t + (v2f){1.f, 1.f};
        float rr = __builtin_amdgcn_rcpf(t.x * t.y);
        h[p] = (v2f){t.y, t.x} * sp(rr);
    }
    // Output dots packed over hidden dim; horizontal add folds the pair.
    v2f a0 = __builtin_elementwise_fma(w.w20[0], h[0], (v2f){w.b20, 0.f});
    v2f a1 = __builtin_elementwise_fma(w.w21[0], h[0], (v2f){w.b21, 0.f});
    v2f a2 = __builtin_elementwise_fma(w.w22[0], h[0], (v2f){w.b22, 0.f});
#pragma unroll
    for (int p = 1; p < 5; ++p) {
        a0 = __builtin_elementwise_fma(w.w20[p], h[p], a0);
        a1 = __builtin_elementwise_fma(w.w21[p], h[p], a1);
        a2 = __builtin_elementwise_fma(w.w22[p], h[p], a2);
    }
    o0 = a0.x + a0.y;
    o1 = a1.x + a1.y;
    o2 = a2.x + a2.y;
}

__global__ void __launch_bounds__(64, 1)
com2net_wavefront(const float* __restrict__ runs,
                  const float* __restrict__ W1, const float* __restrict__ b1,
                  const float* __restrict__ W2, const float* __restrict__ b2,
                  float* __restrict__ out)
{
    const int blk = blockIdx.x;
    const int r   = blk >> 3;              // run index
    const int c   = blk & (CHUNKS - 1);    // time-chunk index
    const int j   = threadIdx.x;           // lane 0..63, owns agents 2j, 2j+1

    const int wstart = c * CLEN;           // first written timestep
    const int wend   = wstart + CLEN;      // one past last written timestep
    const int t0     = wstart - WARM;      // u=0: t = t0 + u - j
    // Chunk 0 must start EXACTLY at t=0 with comm=0 (the reference init).
    const int slo = (c == 0) ? 0 : -0x40000000;

    // 64-row output ring: slot ((t - wstart) & 63), column j. 32 KiB.
    __shared__ v2f ring[64][N_AGENTS / 2];

    const float S = 2.8853900817779268f;  // 2*log2(e), folded into layer 1
    Weights w;
#pragma unroll
    for (int p = 0; p < 5; ++p) {
        w.b1[p]   = (v2f){b1[2 * p] * S, b1[2 * p + 1] * S};
        w.w1x0[p] = (v2f){W1[(2 * p) * 4 + 0] * S, W1[(2 * p + 1) * 4 + 0] * S};
        w.w1x1[p] = (v2f){W1[(2 * p) * 4 + 1] * S, W1[(2 * p + 1) * 4 + 1] * S};
        w.w1cA[p] = (v2f){W1[(2 * p) * 4 + 2] * S, W1[(2 * p + 1) * 4 + 2] * S};
        w.w1cB[p] = (v2f){W1[(2 * p) * 4 + 3] * S, W1[(2 * p + 1) * 4 + 3] * S};
        w.w20[p] = (v2f){-2.f * W2[0 * 10 + 2 * p], -2.f * W2[0 * 10 + 2 * p + 1]};
        w.w21[p] = (v2f){-2.f * W2[1 * 10 + 2 * p], -2.f * W2[1 * 10 + 2 * p + 1]};
        w.w22[p] = (v2f){-2.f * W2[2 * 10 + 2 * p], -2.f * W2[2 * 10 + 2 * p + 1]};
    }
    float s0 = 0.f, s1 = 0.f, s2 = 0.f;
#pragma unroll
    for (int k = 0; k < 10; ++k) {
        s0 += W2[0 * 10 + k];
        s1 += W2[1 * 10 + k];
        s2 += W2[2 * 10 + k];
    }
    w.b20 = b2[0] + s0; w.b21 = b2[1] + s1; w.b22 = b2[2] + s2;

    const float4* __restrict__ xbase =
        (const float4*)(runs + (size_t)r * T_STEPS * N_AGENTS * 2);
    v2f* __restrict__ obase =
        (v2f*)(out + (size_t)r * T_STEPS * N_AGENTS);

    // Replicated recurrence state; zero-init == warm-up / reference init.
    float c1e = 0.f, c2e = 0.f, c1o = 0.f, c2o = 0.f;

    // Clamped row load (OOB lanes re-read row 0/1023; results discarded by
    // the state guards; loads hit cache).
    auto ldrow = [&](int t) -> float4 {
        int tc = t < 0 ? 0 : t;
        tc = tc > T_STEPS - 1 ? T_STEPS - 1 : tc;
        return xbase[tc * (N_AGENTS / 2) + j];
    };

    // One macro-step. pend carries the ring row read at this unroll slot; it
    // is global-stored when the slot comes around next iteration (~6000 cyc
    // later -> lgkmcnt long satisfied, store off the recurrence chain).
    auto step = [&](int u, const float4& x, v2f& pend) {
        const int t = t0 + u - j;
        const bool supd = (t >= slo) & (t < wend);

        // ---- even phase: agent 2j at t ----
        float c2pv = wave_shr1(c2o);
        float o0e, o1e, o2e;
        mlp_eval(w, x.x, x.y, c2pv, c1o, o0e, o1e, o2e);
        c1e = supd ? o1e : c1e;
        c2e = supd ? o2e : c2e;

        // ---- odd phase: agent 2j+1 at t ----
        float c1pv = wave_shl1(c1e);
        float o0o, o1o, o2o;
        mlp_eval(w, x.z, x.w, c2e, c1pv, o0o, o1o, o2o);
        c1o = supd ? o1o : c1o;
        c2o = supd ? o2o : c2o;

        // Store the row this unroll slot ring-read one iteration ago
        // (full-line, lane-contiguous 512B, nontemporal).
        const int mst = u - ST_OFF;
        if ((unsigned)mst < (unsigned)CLEN)
            __builtin_nontemporal_store(
                pend, &obase[(size_t)(wstart + mst) * (N_AGENTS / 2) + j]);

        // Stage this step's outputs: row t0+u-j -> slot (u-j+SHIFT)&63
        // == (in-chunk row)&63.
        ring[(unsigned)(u - j + SHIFT) & 63u][j] = (v2f){o0e, o0o};

        // In-chunk row m = u-RD_OFF just completed (lane 63 wrote it this
        // step); its slot m&63 = (u+SHIFT+1)&63 is overwritten by lane 0 at
        // step u+1 -> read NOW (same-wave DS ops execute in issue order).
        const int mrd = u - RD_OFF;
        if ((unsigned)mrd < (unsigned)CLEN)
            pend = ring[(unsigned)(u + SHIFT + 1) & 63u][j];
    };

    // Distance-4 register prefetch pipeline, manual unroll-by-4.
    float4 X0 = ldrow(t0 + 0 - j);
    float4 X1 = ldrow(t0 + 1 - j);
    float4 X2 = ldrow(t0 + 2 - j);
    float4 X3 = ldrow(t0 + 3 - j);

    v2f p0 = (v2f){0.f, 0.f}, p1 = p0, p2 = p0, p3 = p0;

    for (int u = 0; u < USTEPS; u += 4) {   // 240 = 4*60 iters
        step(u + 0, X0, p0); X0 = ldrow(t0 + u + 4 - j);
        step(u + 1, X1, p1); X1 = ldrow(t0 + u + 5 - j);
        step(u + 2, X2, p2); X2 = ldrow(t0 + u + 6 - j);
        step(u + 3, X3, p3); X3 = ldrow(t0 + u + 7 - j);
    }

    // Epilogue: rows read in the final iteration (u=236..238 -> rows
    // CLEN-3..CLEN-1) are still in p0..p2 ((m+RD_OFF)%4 = 0,1,2); p3's
    // final read was gated off (mrd=128 at u=239).
    __builtin_nontemporal_store(
        p0, &obase[(size_t)(wstart + CLEN - 3) * (N_AGENTS / 2) + j]);
    __builtin_nontemporal_store(
        p1, &obase[(size_t)(wstart + CLEN - 2) * (N_AGENTS / 2) + j]);
    __builtin_nontemporal_store(
        p2, &obase[(size_t)(wstart + CLEN - 1) * (N_AGENTS / 2) + j]);
}

extern "C" void kernel_launch(void* const* d_in, const int* in_sizes, int n_in,
                              void* d_out, int out_size, void* d_ws, size_t ws_size,
                              hipStream_t stream) {
    const float* runs = (const float*)d_in[0];
    const float* W1   = (const float*)d_in[1];
    const float* b1   = (const float*)d_in[2];
    const float* W2   = (const float*)d_in[3];
    const float* b2   = (const float*)d_in[4];
    float* out = (float*)d_out;

    const int R = 128;
    com2net_wavefront<<<R * CHUNKS, 64, 0, stream>>>(runs, W1, b1, W2, b2, out);
}